// Round 5
// baseline (901.696 us; speedup 1.0000x reference)
//
#include <hip/hip_runtime.h>
#include <float.h>

// VQ-VAE vector quantizer forward, MI355X fp32.
// x: [B=32, C=64, H=64, W=64] fp32; emb: [K=512, D=64] fp32.
// out flat (b, h*w, c): out[g*64 + c] = emb[argmin_k ||x_g - emb_k||^2][c].
//
// R5: barrier-free fp32 GEMM + fused argmin.
//  - pre-kernel: embT[c][k] (128 KB) + esq[k] into d_ws  (ws >= 133120 B)
//  - main: A-frags from LDS xs[c][pos] (33 KB -> 4 blocks/CU, 8 waves/CU),
//    B-frags straight from global embT (L2/L1-hot, coalesced dwordx4,
//    8-way lane broadcast), 8x8 register tile, depth-2 ping-pong prefetch
//    of both operands. No __syncthreads in the k-loop.

#define HWD 4096   // H*W
#define CD  64     // C == D
#define KD  512
#define PT  128    // positions per block (2 waves)

__global__ void vq_pre_kernel(const float* __restrict__ emb,
                              float* __restrict__ esq,
                              float* __restrict__ embT) {
    int k = blockIdx.x * 256 + threadIdx.x;      // [0, 512)
    const float* er = emb + (size_t)k * CD;
    float s = 0.f;
    #pragma unroll
    for (int c = 0; c < CD; ++c) {
        float v = er[c];
        s = fmaf(v, v, s);
        embT[(size_t)c * KD + k] = v;            // coalesced across lanes
    }
    esq[k] = s;
}

__launch_bounds__(128, 2)
__global__ void vq_main_kernel(const float* __restrict__ x,
                               const float* __restrict__ emb,
                               const float* __restrict__ esq_g,
                               const float* __restrict__ embT,
                               float* __restrict__ out) {
    const int tid  = threadIdx.x;
    const int lane = tid & 63;
    const int wv   = __builtin_amdgcn_readfirstlane(tid >> 6);  // 0/1
    const int kl   = lane & 7;    // k-group   [0,8): 8 codes
    const int pl   = lane >> 3;   // pos-group [0,8): 8 positions

    const int g0 = blockIdx.x << 7;   // 128 positions per block
    const int b  = g0 >> 12;          // 128 | 4096: no b straddle
    const int n0 = g0 & 4095;

    __shared__ __align__(16) float xs[CD][PT];   // 32 KB, [c][pos]
    __shared__ int bk_s[PT];

    // ---- stage x tile [c][pos]: 2048 float4, 16/thread, coalesced ----
    const float* xg = x + (size_t)b * (CD * HWD) + n0;
    #pragma unroll
    for (int i = 0; i < 16; ++i) {
        int fq = i * 128 + tid;
        int c  = fq >> 5;
        int q  = fq & 31;
        float4 v = *(const float4*)(xg + (size_t)c * HWD + q * 4);
        *(float4*)&xs[c][q * 4] = v;
    }
    __syncthreads();   // the ONLY pre-merge barrier

    const float* ap = &xs[0][wv * 64 + pl * 8];  // 2-way bank alias: free
    const float* bp = embT + kl * 8;

    float bestd[8]; int bestk[8];
    #pragma unroll
    for (int p = 0; p < 8; ++p) { bestd[p] = FLT_MAX; bestk[p] = 0; }

    for (int nt = 0; nt < KD / 64; ++nt) {
        const float* bpt = bp + nt * 64;
        // esq for this lane's 8 codes: issued now, consumed after the c-loop
        float4 eqa = *(const float4*)(esq_g + nt * 64 + kl * 8);
        float4 eqb = *(const float4*)(esq_g + nt * 64 + kl * 8 + 4);

        float C[8][8];
        #pragma unroll
        for (int p = 0; p < 8; ++p)
            #pragma unroll
            for (int j = 0; j < 8; ++j) C[p][j] = 0.f;

        // depth-2 ping-pong prefetch (covers ~120cyc LDS / ~300cyc L2)
        float4 a0[2], a1[2], b0[2], b1[2];
        #pragma unroll
        for (int s = 0; s < 2; ++s) {
            a0[s] = *(const float4*)(ap + s * PT);
            a1[s] = *(const float4*)(ap + s * PT + 4);
            b0[s] = *(const float4*)(bpt + (size_t)s * KD);
            b1[s] = *(const float4*)(bpt + (size_t)s * KD + 4);
        }

        #pragma unroll
        for (int c = 0; c < CD; ++c) {
            const int s = c & 1;
            float4 A0 = a0[s], A1 = a1[s], B0 = b0[s], B1 = b1[s];
            if (c + 2 < CD) {   // compile-time after unroll
                a0[s] = *(const float4*)(ap + (c + 2) * PT);
                a1[s] = *(const float4*)(ap + (c + 2) * PT + 4);
                b0[s] = *(const float4*)(bpt + (size_t)(c + 2) * KD);
                b1[s] = *(const float4*)(bpt + (size_t)(c + 2) * KD + 4);
            }
            float av[8] = {A0.x, A0.y, A0.z, A0.w, A1.x, A1.y, A1.z, A1.w};
            float bv[8] = {B0.x, B0.y, B0.z, B0.w, B1.x, B1.y, B1.z, B1.w};
            #pragma unroll
            for (int p = 0; p < 8; ++p)
                #pragma unroll
                for (int j = 0; j < 8; ++j)
                    C[p][j] = fmaf(av[p], bv[j], C[p][j]);
        }

        // distances + running argmin (j ascending, strict <: lowest k ties)
        float eq[8] = {eqa.x, eqa.y, eqa.z, eqa.w, eqb.x, eqb.y, eqb.z, eqb.w};
        const int kb0 = nt * 64 + kl * 8;
        #pragma unroll
        for (int p = 0; p < 8; ++p)
            #pragma unroll
            for (int j = 0; j < 8; ++j) {
                float d = fmaf(-2.f, C[p][j], eq[j]);
                if (d < bestd[p]) { bestd[p] = d; bestk[p] = kb0 + j; }
            }
    }

    // ---- cross-lane argmin over kl (lane bits 0..2), composite tie pred ----
    #pragma unroll
    for (int m = 1; m <= 4; m <<= 1) {
        #pragma unroll
        for (int p = 0; p < 8; ++p) {
            float od = __shfl_xor(bestd[p], m, 64);
            int   ok = __shfl_xor(bestk[p], m, 64);
            bool take = (od < bestd[p]) || (od == bestd[p] && ok < bestk[p]);
            if (take) { bestd[p] = od; bestk[p] = ok; }
        }
    }
    if (kl == 0) {
        #pragma unroll
        for (int p = 0; p < 8; ++p)
            bk_s[wv * 64 + pl * 8 + p] = bestk[p];
    }
    __syncthreads();

    // ---- gather epilogue: wave-uniform rows, 256-B coalesced, batched ----
    const size_t ob = (size_t)g0 * CD;
    for (int it = 0; it < 64; it += 4) {
        float v[4]; int pp[4];
        #pragma unroll
        for (int j = 0; j < 4; ++j) {
            int p = (it + j) * 2 + wv;
            pp[j] = p;
            v[j]  = emb[bk_s[p] * CD + lane];   // L2-hot
        }
        #pragma unroll
        for (int j = 0; j < 4; ++j)
            out[ob + (size_t)pp[j] * CD + lane] = v[j];
    }
}

extern "C" void kernel_launch(void* const* d_in, const int* in_sizes, int n_in,
                              void* d_out, int out_size, void* d_ws, size_t ws_size,
                              hipStream_t stream) {
    const float* x   = (const float*)d_in[0];   // 32*64*64*64
    const float* emb = (const float*)d_in[1];   // 512*64
    float* out  = (float*)d_out;                // 8388608 floats
    float* esq  = (float*)d_ws;                 // 512 floats
    float* embT = esq + KD;                     // 64*512 floats (uses 133120 B of ws)

    vq_pre_kernel<<<2, 256, 0, stream>>>(emb, esq, embT);
    vq_main_kernel<<<1024, 128, 0, stream>>>(x, emb, esq, embT, out);
}

// Round 6
// 217.741 us; speedup vs baseline: 4.1411x; 4.1411x over previous
//
#include <hip/hip_runtime.h>
#include <float.h>

// VQ-VAE vector quantizer forward, MI355X fp32.
// x: [B=32, C=64, H=64, W=64] fp32; emb: [K=512, D=64] fp32.
// out flat (b, h*w, c): out[g*64 + c] = emb[argmin_k ||x_g - emb_k||^2][c].
//
// R6: fp32 GEMM + fused argmin, 16x8 register tile (6 ds_read_b128 per
// 128 fma -> LDS:VALU issue ratio 1.125, vs 1.5 at 8x8, 3.0 at 4x4).
// Block = 128 thr (2 waves), PT=128 pos (xs 32 KB) + KT=128 es tile
// (32 KB, k-split across the 2 waves) = exactly 64 KB -> 2 blocks/CU.
// es staging is register-prefetched one nt ahead (global loads issued
// between barriers, land during compute). Depth-2 ping-pong on frag reads.
// B operand NEVER comes from global in the k-loop (R5 lesson: 1.38 GB HBM).

#define HWD 4096   // H*W
#define CD  64     // C == D
#define KD  512
#define PT  128    // positions per block
#define KT  128    // k per es tile (wave w owns columns w*64 .. w*64+63)

__global__ void vq_esq_kernel(const float* __restrict__ emb, float* __restrict__ esq) {
    int k = blockIdx.x * 256 + threadIdx.x;
    if (k < KD) {
        const float* er = emb + (size_t)k * CD;
        float s = 0.f;
        #pragma unroll
        for (int c = 0; c < CD; ++c) s = fmaf(er[c], er[c], s);
        esq[k] = s;
    }
}

__launch_bounds__(128, 1)
__global__ void vq_main_kernel(const float* __restrict__ x,
                               const float* __restrict__ emb,
                               const float* __restrict__ esq_g,
                               float* __restrict__ out) {
    const int tid  = threadIdx.x;
    const int lane = tid & 63;
    const int wv   = __builtin_amdgcn_readfirstlane(tid >> 6);  // 0/1
    const int kl   = lane & 7;    // k-group   [0,8): 8 codes
    const int pl   = lane >> 3;   // pos-group [0,8): 16 positions

    const int g0 = blockIdx.x << 7;   // 128 positions per block
    const int b  = g0 >> 12;          // 128 | 4096: no b straddle
    const int n0 = g0 & 4095;

    __shared__ __align__(16) float xs[CD][PT];   // 32768 B
    __shared__ __align__(16) float es[CD][KT];   // 32768 B  (total = 65536 exactly)

    // ---- stage x tile [c][pos]: 2048 float4, 16/thread, coalesced ----
    const float* xg = x + (size_t)b * (CD * HWD) + n0;
    #pragma unroll
    for (int i = 0; i < 16; ++i) {
        int fq = i * 128 + tid;
        int c  = fq >> 5;
        int q  = fq & 31;
        float4 v = *(const float4*)(xg + (size_t)c * HWD + q * 4);
        *(float4*)&xs[c][q * 4] = v;
    }

    // ---- prefetch nt=0 emb rows into registers (thread stages k=tid) ----
    float4 er[16];
    {
        const float* eg = emb + (size_t)tid * CD;
        #pragma unroll
        for (int j = 0; j < 16; ++j) er[j] = *(const float4*)(eg + j * 4);
    }
    __syncthreads();   // xs ready; es writes ordered after this

    float bestd[16]; int bestk[16];
    #pragma unroll
    for (int p = 0; p < 16; ++p) { bestd[p] = FLT_MAX; bestk[p] = 0; }

    const float* ap = &xs[0][pl * 16];          // 16 positions (64-B aligned)
    const float* bp = &es[0][wv * 64 + kl * 8]; // 8 codes      (32-B aligned)

    for (int nt = 0; nt < KD / KT; ++nt) {
        // write prefetched emb rows into es (transpose: es[c][tid] = emb[k][c]);
        // bank = tid%32 fixed per thread -> conflict-free wave writes
        {
            const float* erf = (const float*)er;
            #pragma unroll
            for (int c = 0; c < CD; ++c) es[c][tid] = erf[c];
        }
        // issue next tile's global loads now; they land during compute below
        if (nt + 1 < KD / KT) {
            const float* eg = emb + (size_t)((nt + 1) * KT + tid) * CD;
            #pragma unroll
            for (int j = 0; j < 16; ++j) er[j] = *(const float4*)(eg + j * 4);
        }
        // esq for this lane's 8 codes (L2-hot, consumed after c-loop)
        float4 eqa = *(const float4*)(esq_g + nt * KT + wv * 64 + kl * 8);
        float4 eqb = *(const float4*)(esq_g + nt * KT + wv * 64 + kl * 8 + 4);
        __syncthreads();   // es ready

        float C[16][8];
        #pragma unroll
        for (int p = 0; p < 16; ++p)
            #pragma unroll
            for (int j = 0; j < 8; ++j) C[p][j] = 0.f;

        // depth-2 ping-pong prefetch of LDS frags
        float4 A[2][4], Bv[2][2];
        #pragma unroll
        for (int s = 0; s < 2; ++s) {
            #pragma unroll
            for (int q = 0; q < 4; ++q) A[s][q] = *(const float4*)(ap + s * PT + q * 4);
            Bv[s][0] = *(const float4*)(bp + s * KT);
            Bv[s][1] = *(const float4*)(bp + s * KT + 4);
        }

        #pragma unroll 2
        for (int c = 0; c < CD; ++c) {
            const int s = c & 1;
            float av[16], bv[8];
            #pragma unroll
            for (int q = 0; q < 4; ++q) {
                av[q * 4 + 0] = A[s][q].x; av[q * 4 + 1] = A[s][q].y;
                av[q * 4 + 2] = A[s][q].z; av[q * 4 + 3] = A[s][q].w;
            }
            bv[0] = Bv[s][0].x; bv[1] = Bv[s][0].y; bv[2] = Bv[s][0].z; bv[3] = Bv[s][0].w;
            bv[4] = Bv[s][1].x; bv[5] = Bv[s][1].y; bv[6] = Bv[s][1].z; bv[7] = Bv[s][1].w;
            // branch-free prefetch for c+2 (wrap-clamp; last 2 iters load dead data)
            const int cn = (c + 2) & 63;
            #pragma unroll
            for (int q = 0; q < 4; ++q) A[s][q] = *(const float4*)(ap + cn * PT + q * 4);
            Bv[s][0] = *(const float4*)(bp + cn * KT);
            Bv[s][1] = *(const float4*)(bp + cn * KT + 4);
            #pragma unroll
            for (int p = 0; p < 16; ++p)
                #pragma unroll
                for (int j = 0; j < 8; ++j)
                    C[p][j] = fmaf(av[p], bv[j], C[p][j]);
        }

        // distances + running argmin (j ascending, nt ascending, strict <)
        float eq[8] = {eqa.x, eqa.y, eqa.z, eqa.w, eqb.x, eqb.y, eqb.z, eqb.w};
        const int kb0 = nt * KT + wv * 64 + kl * 8;
        #pragma unroll
        for (int p = 0; p < 16; ++p)
            #pragma unroll
            for (int j = 0; j < 8; ++j) {
                float d = fmaf(-2.f, C[p][j], eq[j]);
                if (d < bestd[p]) { bestd[p] = d; bestk[p] = kb0 + j; }
            }

        __syncthreads();   // WAR: all waves done reading es before next staging
    }

    // ---- cross-lane argmin over kl (lane bits 0..2), composite tie pred ----
    #pragma unroll
    for (int m = 1; m <= 4; m <<= 1) {
        #pragma unroll
        for (int p = 0; p < 16; ++p) {
            float od = __shfl_xor(bestd[p], m, 64);
            int   ok = __shfl_xor(bestk[p], m, 64);
            bool take = (od < bestd[p]) || (od == bestd[p] && ok < bestk[p]);
            if (take) { bestd[p] = od; bestk[p] = ok; }
        }
    }

    // ---- cross-wave merge via regions aliased onto es (es is dead now;
    //      last loop barrier ordered all es reads before these writes) ----
    float* sh_d = (float*)&es[0][0];   // [2][128] floats (rows 0-1)
    int*   sh_k = (int*)  &es[2][0];   // [2][128] ints   (rows 2-3)
    int*   bk_s = (int*)  &es[4][0];   // [128]    ints   (row 4)
    if (kl == 0) {
        #pragma unroll
        for (int p = 0; p < 16; ++p) {
            int pos = pl * 16 + p;
            sh_d[wv * 128 + pos] = bestd[p];
            sh_k[wv * 128 + pos] = bestk[p];
        }
    }
    __syncthreads();
    {
        int pos = tid;
        float d0 = sh_d[pos];       int k0 = sh_k[pos];
        float d1 = sh_d[128 + pos]; int k1 = sh_k[128 + pos];
        bool take = (d1 < d0) || (d1 == d0 && k1 < k0);  // wave0 = lower k wins ties
        bk_s[pos] = take ? k1 : k0;
    }
    __syncthreads();

    // ---- gather epilogue: wave-uniform rows, 256-B coalesced, batched ----
    const size_t ob = (size_t)g0 * CD;
    for (int it = 0; it < 64; it += 4) {
        float v[4]; int pp[4];
        #pragma unroll
        for (int j = 0; j < 4; ++j) {
            int p = (it + j) * 2 + wv;
            pp[j] = p;
            v[j]  = emb[bk_s[p] * CD + lane];   // L2-hot
        }
        #pragma unroll
        for (int j = 0; j < 4; ++j)
            out[ob + (size_t)pp[j] * CD + lane] = v[j];
    }
}

extern "C" void kernel_launch(void* const* d_in, const int* in_sizes, int n_in,
                              void* d_out, int out_size, void* d_ws, size_t ws_size,
                              hipStream_t stream) {
    const float* x   = (const float*)d_in[0];   // 32*64*64*64
    const float* emb = (const float*)d_in[1];   // 512*64
    float* out = (float*)d_out;                 // 8388608 floats
    float* esq = (float*)d_ws;                  // 512 floats scratch

    vq_esq_kernel<<<2, 256, 0, stream>>>(emb, esq);
    vq_main_kernel<<<1024, 128, 0, stream>>>(x, emb, esq, out);
}

// Round 7
// 123.786 us; speedup vs baseline: 7.2843x; 1.7590x over previous
//
#include <hip/hip_runtime.h>
#include <float.h>

// VQ-VAE vector quantizer forward, MI355X — bf16 MFMA with exact 3-way split.
// x: [B=32, C=64, H=64, W=64] fp32; emb: [K=512, D=64] fp32.
// out flat (b, h*w, c): out[g*64 + c] = emb[argmin_k ||x_g - emb_k||^2][c].
//
// R7: distances via matrix cores. Each fp32 operand is split v = vh+vm+vl
// (3 bf16; each step is an exact Veltkamp split, residual <= 2^-27|v|).
// dot(x,e) = sum of 6 product classes {hh,hm,mh,hl,mm,lh} x 2 K-chunks
// = 12 chained v_mfma_f32_16x16x32_bf16 into one fp32 accumulator ->
// distance error below np's own fp32 rounding (bf16 shares fp32 exponent
// range: no subnormal flush anywhere). MFMA floor ~21 us vs 54.6 us fp32.
// Block: 256 thr / 4 waves, 256 positions; wave = 64 pos (4 M-tiles),
// walks all 512 k; emb tile (KT=128) split in-block into LDS each nt.
// Verified layouts (m89/m91/m120): A[m=lane&15][k=quad*8+j],
// B[n=lane&15][k=quad*8+j], D col=lane&15, row=quad*4+reg.

typedef __attribute__((ext_vector_type(8))) short  short8;
typedef __attribute__((ext_vector_type(4))) float  floatx4;

#define HWD 4096
#define CD  64
#define KD  512
#define PT  256    // positions per block
#define KT  128    // emb rows staged per nt
#define ESR 72     // es row stride in bf16 elems (pad: 16 rows spread banks)

// round-to-nearest-even fp32 -> bf16 (bit-level; inputs are finite)
__device__ inline unsigned short bf16_rne(float v) {
    unsigned int u = __builtin_bit_cast(unsigned int, v);
    u += 0x7fffu + ((u >> 16) & 1u);
    return (unsigned short)(u >> 16);
}
__device__ inline float bf16_val(unsigned short h) {
    return __builtin_bit_cast(float, (unsigned int)h << 16);
}
// exact 3-way split: v = h + m + l + eps, |eps| <= 2^-27 |v|
__device__ inline void split3(float v, unsigned short& h, unsigned short& m,
                              unsigned short& l) {
    h = bf16_rne(v);
    float r1 = v - bf16_val(h);     // exact in fp32
    m = bf16_rne(r1);
    float r2 = r1 - bf16_val(m);    // exact in fp32
    l = bf16_rne(r2);
}

#define MFMA(A, B, C) __builtin_amdgcn_mfma_f32_16x16x32_bf16((A), (B), (C), 0, 0, 0)

__launch_bounds__(256, 2)
__global__ void vq_mfma_kernel(const float* __restrict__ x,
                               const float* __restrict__ emb,
                               float* __restrict__ out) {
    const int tid  = threadIdx.x;
    const int lane = tid & 63;
    const int wv   = __builtin_amdgcn_readfirstlane(tid >> 6);  // 0..3
    const int n16  = lane & 15;   // m for A, n for B, col for D
    const int quad = lane >> 4;   // k-quad for A/B, row-quad for D

    const int g0 = blockIdx.x << 8;   // 256 positions per block
    const int b  = g0 >> 12;          // 256 | 4096: no b straddle
    const int n0 = g0 & 4095;

    __shared__ unsigned short es_h[KT][ESR];   // 18432 B each
    __shared__ unsigned short es_m[KT][ESR];
    __shared__ unsigned short es_l[KT][ESR];
    __shared__ float esq_p[2 * KT];            // per-half-row |e|^2 partials
    __shared__ int   bk_s[PT];

    // ---- A fragments: load x, split to 3 bf16 frags (held whole kernel) ----
    // pos = g0 + wv*64 + mt*16 + n16 ; k(c) = ch*32 + quad*8 + j
    short8 ah[4][2], am[4][2], al[4][2];
    {
        const float* xb = x + (size_t)b * (CD * HWD) + n0 + wv * 64 + n16;
        #pragma unroll
        for (int mt = 0; mt < 4; ++mt)
            #pragma unroll
            for (int ch = 0; ch < 2; ++ch) {
                #pragma unroll
                for (int j = 0; j < 8; ++j) {
                    float v = xb[(size_t)(ch * 32 + quad * 8 + j) * HWD + mt * 16];
                    unsigned short h, m, l;
                    split3(v, h, m, l);
                    ah[mt][ch][j] = (short)h;
                    am[mt][ch][j] = (short)m;
                    al[mt][ch][j] = (short)l;
                }
            }
    }

    float bestd[16]; int bestk[16];
    #pragma unroll
    for (int i = 0; i < 16; ++i) { bestd[i] = FLT_MAX; bestk[i] = 0; }

    const int lr   = tid >> 1;   // staging: emb row (128 rows)
    const int half = tid & 1;    // staging: c half (32 each)

    for (int nt = 0; nt < KD / KT; ++nt) {
        __syncthreads();   // WAR: prior tile's readers done before restage

        // ---- stage emb tile: split rows nt*128..+127 into es_{h,m,l};
        //      |e|^2 half-row partials into esq_p (esq fused, no pre-kernel)
        {
            const float* eg = emb + (size_t)(nt * KT + lr) * CD + half * 32;
            float s = 0.f;
            #pragma unroll
            for (int q = 0; q < 8; ++q) {
                float4 ev = *(const float4*)(eg + q * 4);
                float vv[4] = {ev.x, ev.y, ev.z, ev.w};
                ushort4 h4, m4, l4;
                unsigned short* hp = (unsigned short*)&h4;
                unsigned short* mp = (unsigned short*)&m4;
                unsigned short* lp = (unsigned short*)&l4;
                #pragma unroll
                for (int i = 0; i < 4; ++i) {
                    s = fmaf(vv[i], vv[i], s);
                    split3(vv[i], hp[i], mp[i], lp[i]);
                }
                int c0 = half * 32 + q * 4;
                *(ushort4*)&es_h[lr][c0] = h4;
                *(ushort4*)&es_m[lr][c0] = m4;
                *(ushort4*)&es_l[lr][c0] = l4;
            }
            esq_p[2 * lr + half] = s;
        }
        __syncthreads();   // RAW: es/esq ready

        // ---- compute: 8 local N-tiles of 16 codes ----
        #pragma unroll 2
        for (int ln = 0; ln < 8; ++ln) {
            const int krow = ln * 16 + n16;            // es row for B-frag
            const unsigned short* ph = &es_h[krow][quad * 8];
            const unsigned short* pm = &es_m[krow][quad * 8];
            const unsigned short* pl = &es_l[krow][quad * 8];
            short8 bh0 = *(const short8*)ph,  bh1 = *(const short8*)(ph + 32);
            short8 bm0 = *(const short8*)pm,  bm1 = *(const short8*)(pm + 32);
            short8 bl0 = *(const short8*)pl,  bl1 = *(const short8*)(pl + 32);
            const float eq = esq_p[2 * krow] + esq_p[2 * krow + 1];
            const int   kv = nt * KT + ln * 16 + n16;  // this lane's code col

            floatx4 acc[4];
            #pragma unroll
            for (int mt = 0; mt < 4; ++mt) acc[mt] = (floatx4){0.f, 0.f, 0.f, 0.f};

            // small -> large accumulation; mt-inner gives 4-way MFMA ILP
            #define STEP(AR, B0, B1)                                          \
                { _Pragma("unroll")                                           \
                  for (int mt = 0; mt < 4; ++mt) acc[mt] = MFMA(AR[mt][0], B0, acc[mt]); \
                  _Pragma("unroll")                                           \
                  for (int mt = 0; mt < 4; ++mt) acc[mt] = MFMA(AR[mt][1], B1, acc[mt]); }
            STEP(al, bh0, bh1)   // x_l * e_h   (~2^-18)
            STEP(am, bm0, bm1)   // x_m * e_m   (~2^-18)
            STEP(ah, bl0, bl1)   // x_h * e_l   (~2^-18)
            STEP(am, bh0, bh1)   // x_m * e_h   (~2^-9)
            STEP(ah, bm0, bm1)   // x_h * e_m   (~2^-9)
            STEP(ah, bh0, bh1)   // x_h * e_h   (O(1))
            #undef STEP

            // distances + running argmin (k ascending across nt/ln: strict <)
            #pragma unroll
            for (int mt = 0; mt < 4; ++mt)
                #pragma unroll
                for (int r = 0; r < 4; ++r) {
                    float d = fmaf(-2.f, acc[mt][r], eq);
                    int idx = mt * 4 + r;
                    if (d < bestd[idx]) { bestd[idx] = d; bestk[idx] = kv; }
                }
        }
    }

    // ---- cross-lane argmin over the 16 code-columns (lane bits 0..3) ----
    #pragma unroll
    for (int msk = 1; msk <= 8; msk <<= 1)
        #pragma unroll
        for (int i = 0; i < 16; ++i) {
            float od = __shfl_xor(bestd[i], msk, 64);
            int   ok = __shfl_xor(bestk[i], msk, 64);
            bool take = (od < bestd[i]) || (od == bestd[i] && ok < bestk[i]);
            if (take) { bestd[i] = od; bestk[i] = ok; }
        }
    // D row = quad*4 + r within tile -> pos = wv*64 + mt*16 + quad*4 + r
    if (n16 == 0) {
        #pragma unroll
        for (int mt = 0; mt < 4; ++mt)
            #pragma unroll
            for (int r = 0; r < 4; ++r)
                bk_s[wv * 64 + mt * 16 + quad * 4 + r] = bestk[mt * 4 + r];
    }
    __syncthreads();

    // ---- gather epilogue: wave-uniform rows, 256-B coalesced, batched ----
    const size_t ob = (size_t)g0 * CD;
    for (int it = 0; it < 16; ++it) {
        float v[4]; int pp[4];
        #pragma unroll
        for (int j = 0; j < 4; ++j) {
            int p = (it * 4 + j) * 4 + wv;
            pp[j] = p;
            v[j]  = emb[bk_s[p] * CD + lane];   // L2-hot fp32 row
        }
        #pragma unroll
        for (int j = 0; j < 4; ++j)
            out[ob + (size_t)pp[j] * CD + lane] = v[j];
    }
}

extern "C" void kernel_launch(void* const* d_in, const int* in_sizes, int n_in,
                              void* d_out, int out_size, void* d_ws, size_t ws_size,
                              hipStream_t stream) {
    const float* x   = (const float*)d_in[0];   // 32*64*64*64
    const float* emb = (const float*)d_in[1];   // 512*64
    float* out = (float*)d_out;                 // 8388608 floats

    vq_mfma_kernel<<<512, 256, 0, stream>>>(x, emb, out);
}